// Round 10
// baseline (193.708 us; speedup 1.0000x reference)
//
#include <hip/hip_runtime.h>
#include <hip/hip_fp16.h>

// Problem constants (match reference)
#define BB      2048
#define CC      1024
#define FF      128
#define NBLK    256      // phase-0/1 grid: 1 block/CU
#define RPB     8        // GEMM rows per block (NBLK*RPB == BB)
#define TPB     512      // 8 waves/block
#define NITER   10
#define SUBR    8        // colsum spread: [t][k][c] layout, wave-coalesced
#define NIB     64       // iteration blocks (bid < NIB survive past barrier B)
#define RPIB    32       // rows per iteration block (NIB*RPIB == BB)
#define SCALING_F (2048.0f / 100000.0f)
#define CPAD    16       // pad sync counters to own 64B line

// Static device storage: no hipMalloc, graph-capture safe. ALL cross-block
// data moves through agent-scope __hip_atomic_* (serviced at the IF/LLC
// coherence point, bypassing the non-coherent per-XCD L2s) — the transport
// proven correct in rounds 3-7. Round 9's sc0/sc1 asm transport produced
// 1.3e-4 errors (unverified coherence semantics) and is REMOVED.
// All sync counters MONOTONIC (never reset); windows from per-launch epoch.
__device__ unsigned g_epoch;                  // 256 increments per launch
__device__ unsigned g_leafA[2 * 8 * CPAD];    // 256-wide tree (slots A=0,B=1)
__device__ unsigned g_rootA[2 * CPAD];
__device__ unsigned g_relA [2 * CPAD];
__device__ unsigned g_leafB[NITER * 8 * CPAD];// 64-wide tree (slots t=0..9)
__device__ unsigned g_rootB[NITER * CPAD];
__device__ unsigned g_relB [NITER * CPAD];
__device__ float g_meanPart[NBLK];
__device__ float g_colsum[NITER * SUBR * CC]; // [t][k][c] — c contiguous
__device__ unsigned long long g_K64[BB * CC / 2]; // 8 MB K spill, 2 floats/op

__device__ __forceinline__ float atomLoadF(const float* p) {
    return __hip_atomic_load(p, __ATOMIC_RELAXED, __HIP_MEMORY_SCOPE_AGENT);
}
__device__ __forceinline__ void atomStoreF(float* p, float v) {
    __hip_atomic_store(p, v, __ATOMIC_RELAXED, __HIP_MEMORY_SCOPE_AGENT);
}
__device__ __forceinline__ unsigned atomAddU(unsigned* p) {
    return __hip_atomic_fetch_add(p, 1u, __ATOMIC_RELAXED,
                                  __HIP_MEMORY_SCOPE_AGENT);
}
__device__ __forceinline__ unsigned loadU(const unsigned* p) {
    return __hip_atomic_load(p, __ATOMIC_RELAXED, __HIP_MEMORY_SCOPE_AGENT);
}
__device__ __forceinline__ void storeU(unsigned* p, unsigned v) {
    __hip_atomic_store(p, v, __ATOMIC_RELAXED, __HIP_MEMORY_SCOPE_AGENT);
}
__device__ __forceinline__ unsigned long long
atomLoadU64(const unsigned long long* p) {
    return __hip_atomic_load(p, __ATOMIC_RELAXED, __HIP_MEMORY_SCOPE_AGENT);
}
__device__ __forceinline__ void
atomStoreU64(unsigned long long* p, unsigned long long v) {
    __hip_atomic_store(p, v, __ATOMIC_RELAXED, __HIP_MEMORY_SCOPE_AGENT);
}
__device__ __forceinline__ unsigned long long packF2(float a, float b) {
    union { float f[2]; unsigned long long u; } x;
    x.f[0] = a; x.f[1] = b; return x.u;
}
__device__ __forceinline__ float2 unpackF2(unsigned long long u) {
    union { float f[2]; unsigned long long u; } x;
    x.u = u; return make_float2(x.f[0], x.f[1]);
}

__global__ void __launch_bounds__(TPB)
fused_sinkhorn(const int* __restrict__ users, const int* __restrict__ items,
               const float* __restrict__ D, const float* __restrict__ caps,
               const float* __restrict__ iemb, const float* __restrict__ uemb,
               float* __restrict__ out) {
    const int bid = blockIdx.x, tid = threadIdx.x;
    const int r0 = bid * RPB;

    // LDS ~132.3 KB/block (1 block/CU). dott (phases 0-1) overlays the
    // 128 KB K tile (iteration blocks only) — disjoint lifetimes.
    __shared__ __align__(16) union {
        __half dott[RPB][CC];          // 16 KB
        float  Kt[RPIB * CC];          // 128 KB
    } kk;
    __shared__ __align__(16) union { float ue[RPB][FF]; float v[CC]; } uv;
    __shared__ float  ush[RPIB];
    __shared__ float  red[TPB / 64];
    __shared__ float  s2sh;
    __shared__ unsigned s_epoch;

    // ---------------- phase 0 (all 256 blocks) ------------------------------
    if (tid == 0) s_epoch = atomAddU(&g_epoch) >> 8;   // e = launch index

    const float4* Dg  = (const float4*)(D + ((size_t)r0 << 10));
    const int4*   it4 = (const int4*)(items + ((size_t)r0 << 10));
    float4 d_reg[4];
    int4   it_reg[4];
    #pragma unroll
    for (int k = 0; k < 4; ++k) d_reg[k]  = Dg[tid + k * TPB];
    #pragma unroll
    for (int k = 0; k < 4; ++k) it_reg[k] = it4[tid + k * TPB];

    // caps for this thread's two owned columns (iteration blocks use these)
    const float cap0 = caps[tid]       * SCALING_F;
    const float cap1 = caps[tid + 512] * SCALING_F;

    // zero colsum accumulators (visible at IF)
    for (int i = bid * TPB + tid; i < NITER * SUBR * CC; i += NBLK * TPB)
        atomStoreF(&g_colsum[i], 0.0f);

    // stage 8 user embeddings
    if (tid < 256) {
        int r = tid >> 5, f4 = tid & 31;
        int u = users[r0 + r];
        ((float4*)uv.ue[r])[f4] = ((const float4*)(uemb + (size_t)u * FF))[f4];
    }

    // block partial sum of D
    float p = 0.0f;
    #pragma unroll
    for (int k = 0; k < 4; ++k) {
        float4 d = d_reg[k];
        p += d.x + d.y + d.z + d.w;
    }
    #pragma unroll
    for (int off = 32; off > 0; off >>= 1) p += __shfl_down(p, off, 64);
    if ((tid & 63) == 0) red[tid >> 6] = p;
    __syncthreads();                 // publishes uv.ue, red, s_epoch
    const unsigned e = s_epoch;
    if (tid == 0) {
        float s = 0.0f;
        #pragma unroll
        for (int k = 0; k < TPB / 64; ++k) s += red[k];
        atomStoreF(&g_meanPart[bid], s);
    }

    // dot GEMM: dott[r][j] = ue[r].iemb[j]; 2 j-columns share each LDS read
    {
        const float4* us  = (const float4*)uv.ue;
        const float4* ip0 = (const float4*)(iemb + (size_t)tid * FF);
        const float4* ip1 = (const float4*)(iemb + (size_t)(tid + 512) * FF);
        float acc0[RPB] = {}, acc1[RPB] = {};
        for (int f4 = 0; f4 < FF / 4; ++f4) {
            float4 a0 = ip0[f4], a1 = ip1[f4];
            #pragma unroll
            for (int r = 0; r < RPB; ++r) {
                float4 b = us[r * (FF / 4) + f4];
                acc0[r] += a0.x * b.x + a0.y * b.y + a0.z * b.z + a0.w * b.w;
                acc1[r] += a1.x * b.x + a1.y * b.y + a1.z * b.z + a1.w * b.w;
            }
        }
        #pragma unroll
        for (int r = 0; r < RPB; ++r) {
            kk.dott[r][tid]       = __float2half(acc0[r]);
            kk.dott[r][tid + 512] = __float2half(acc1[r]);
        }
    }

    // barrier A (256-wide tree): colsum zeros + meanPart complete
    __syncthreads();
    if (tid == 0) {
        unsigned rl = atomAddU(&g_leafA[(0 * 8 + (bid >> 5)) * CPAD]);
        if (rl == e * 32 + 31) {
            unsigned rr = atomAddU(&g_rootA[0 * CPAD]);
            if (rr == e * 8 + 7) storeU(&g_relA[0 * CPAD], e + 1u);
        }
        while ((int)(loadU(&g_relA[0 * CPAD]) - (e + 1u)) < 0) ;
    }
    __syncthreads();

    // ---------------- phase 1: s2, K built in regs -> spilled (atomics) -----
    if (tid < 64) {
        float s = 0.0f;
        #pragma unroll
        for (int k = 0; k < NBLK / 64; ++k)
            s += atomLoadF(&g_meanPart[tid + 64 * k]);
        #pragma unroll
        for (int off = 32; off > 0; off >>= 1) s += __shfl_down(s, off, 64);
        if (tid == 0) s2sh = 5.0f * (float)(BB * CC) / s;
    }
    __syncthreads();
    const float s2 = s2sh;
    {
        unsigned long long* dst64 = g_K64 + (size_t)bid * (RPB * CC / 2);
        #pragma unroll
        for (int k = 0; k < 4; ++k) {
            int    i  = tid + k * TPB;      // float4 index in block's 8 rows
            int4   iv = it_reg[k];
            float4 d  = d_reg[k];
            int    r  = i >> 8;
            float kx = __expf(5.0f * __half2float(kk.dott[r][iv.x]) - s2 * d.x);
            float ky = __expf(5.0f * __half2float(kk.dott[r][iv.y]) - s2 * d.y);
            float kz = __expf(5.0f * __half2float(kk.dott[r][iv.z]) - s2 * d.z);
            float kw = __expf(5.0f * __half2float(kk.dott[r][iv.w]) - s2 * d.w);
            atomStoreU64(&dst64[2 * i],     packF2(kx, ky));
            atomStoreU64(&dst64[2 * i + 1], packF2(kz, kw));
        }
    }

    // barrier B (256-wide): all K atomic-stores performed at IF. Blocks >=
    // NIB arrive and EXIT; the 64 iteration blocks spin for the release.
    __syncthreads();   // each wave drains its stores (vmcnt) before arrival
    if (tid == 0) {
        unsigned rl = atomAddU(&g_leafA[(1 * 8 + (bid >> 5)) * CPAD]);
        if (rl == e * 32 + 31) {
            unsigned rr = atomAddU(&g_rootA[1 * CPAD]);
            if (rr == e * 8 + 7) storeU(&g_relA[1 * CPAD], e + 1u);
        }
    }
    if (bid >= NIB) return;
    if (tid == 0)
        while ((int)(loadU(&g_relA[1 * CPAD]) - (e + 1u)) < 0) ;
    __syncthreads();

    // ---------------- iteration blocks: reload 32 rows of K into LDS --------
    // 32x 8B agent-scope atomic loads/thread, batched 8-at-a-time so the
    // compiler pipelines each batch before the dependent LDS writes.
    {
        const unsigned long long* src64 = g_K64 + (size_t)bid * (RPIB * CC / 2);
        float2* kt2 = (float2*)kk.Kt;
        for (int m = 0; m < 32; m += 8) {
            unsigned long long tmp[8];
            #pragma unroll
            for (int q = 0; q < 8; ++q)
                tmp[q] = atomLoadU64(&src64[tid + (m + q) * TPB]);
            #pragma unroll
            for (int q = 0; q < 8; ++q)
                kt2[tid + (m + q) * TPB] = unpackF2(tmp[q]);
        }
    }
    __syncthreads();
    const float*  Ktf = kk.Kt;
    const float4* Kt4 = (const float4*)kk.Kt;

    // ---------------- Sinkhorn iterations (64 blocks) ------------------------
    for (int t = 0; t < NITER; ++t) {
        // v-fill: round-6 proven scalar path (compiler pipelines 16 loads)
        if (t == 0) {
            uv.v[tid]       = 1.0f;
            uv.v[tid + 512] = 1.0f;
        } else {
            const float* base = g_colsum + (size_t)(t - 1) * SUBR * CC;
            float t0[SUBR], t1[SUBR];
            #pragma unroll
            for (int k = 0; k < SUBR; ++k) t0[k] = atomLoadF(&base[k * CC + tid]);
            #pragma unroll
            for (int k = 0; k < SUBR; ++k) t1[k] = atomLoadF(&base[k * CC + tid + 512]);
            float s0 = 0.0f, s1 = 0.0f;
            #pragma unroll
            for (int k = 0; k < SUBR; ++k) { s0 += t0[k]; s1 += t1[k]; }
            uv.v[tid]       = cap0 / s0;
            uv.v[tid + 512] = cap1 / s1;
        }
        __syncthreads();

        // u_r = 1/(K v)_r : wave w handles rows 4w..4w+3
        {
            int w = tid >> 6, l = tid & 63;
            const float4* v4 = (const float4*)uv.v;
            #pragma unroll
            for (int rr = 0; rr < 4; ++rr) {
                int row = (w << 2) + rr;
                const float4* kr = Kt4 + row * (CC / 4);
                float pp = 0.0f;
                #pragma unroll
                for (int i2 = 0; i2 < 4; ++i2) {
                    float4 k = kr[l + i2 * 64], v = v4[l + i2 * 64];
                    pp += k.x * v.x + k.y * v.y + k.z * v.z + k.w * v.w;
                }
                #pragma unroll
                for (int off = 32; off > 0; off >>= 1)
                    pp += __shfl_down(pp, off, 64);
                if (l == 0) ush[row] = 1.0f / pp;
            }
        }
        __syncthreads();

        // colsum[t] += K^T u : 2 wave-coalesced atomicAdds per thread
        {
            float* cb = g_colsum + ((size_t)t * SUBR + (bid & (SUBR - 1))) * CC;
            float sA = 0.0f, sB = 0.0f;
            #pragma unroll
            for (int r = 0; r < RPIB; ++r) {
                float u = ush[r];
                sA += Ktf[r * CC + tid]       * u;
                sB += Ktf[r * CC + tid + 512] * u;
            }
            atomicAdd(&cb[tid],       sA);
            atomicAdd(&cb[tid + 512], sB);
        }

        // 64-wide tree barrier (8 leaves x 8 blocks), slot t
        __syncthreads();   // drains adds (vmcnt) before arrival
        if (tid == 0) {
            unsigned rl = atomAddU(&g_leafB[(t * 8 + (bid >> 3)) * CPAD]);
            if (rl == e * 8 + 7) {
                unsigned rr = atomAddU(&g_rootB[t * CPAD]);
                if (rr == e * 8 + 7) storeU(&g_relB[t * CPAD], e + 1u);
            }
            while ((int)(loadU(&g_relB[t * CPAD]) - (e + 1u)) < 0) ;
        }
        __syncthreads();
    }

    // ---------------- final: v10 from colsum[9], P = K * u10 (x) v10 --------
    {
        const float* base = g_colsum + (size_t)(NITER - 1) * SUBR * CC;
        float t0[SUBR], t1[SUBR];
        #pragma unroll
        for (int k = 0; k < SUBR; ++k) t0[k] = atomLoadF(&base[k * CC + tid]);
        #pragma unroll
        for (int k = 0; k < SUBR; ++k) t1[k] = atomLoadF(&base[k * CC + tid + 512]);
        float s0 = 0.0f, s1 = 0.0f;
        #pragma unroll
        for (int k = 0; k < SUBR; ++k) { s0 += t0[k]; s1 += t1[k]; }
        uv.v[tid]       = cap0 / s0;
        uv.v[tid + 512] = cap1 / s1;
    }
    __syncthreads();

    float4* o4 = (float4*)out + (size_t)bid * (RPIB * CC / 4);
    #pragma unroll
    for (int c = 0; c < 16; ++c) {
        int    i   = tid + c * TPB;
        int    row = i >> 8;
        float4 kv  = Kt4[i];
        float  ur  = ush[row];
        float4 v   = ((const float4*)uv.v)[i & 255];
        float4 pv;
        pv.x = kv.x * ur * v.x;  pv.y = kv.y * ur * v.y;
        pv.z = kv.z * ur * v.z;  pv.w = kv.w * ur * v.w;
        o4[i] = pv;
    }
}

extern "C" void kernel_launch(void* const* d_in, const int* in_sizes, int n_in,
                              void* d_out, int out_size, void* d_ws, size_t ws_size,
                              hipStream_t stream) {
    const int*   users = (const int*)d_in[0];
    const int*   items = (const int*)d_in[1];
    const float* D     = (const float*)d_in[2];
    const float* caps  = (const float*)d_in[3];
    const float* iemb  = (const float*)d_in[4];
    const float* uemb  = (const float*)d_in[5];
    float* out = (float*)d_out;

    // Plain launch (graph-capture friendly). 256 blocks, ~132.3 KB LDS, 8
    // waves -> 1 block/CU on 256 CUs: all co-resident, monotonic barriers
    // safe. Blocks >= 64 exit after the K-spill barrier.
    hipLaunchKernelGGL(fused_sinkhorn, dim3(NBLK), dim3(TPB), 0, stream,
                       users, items, D, caps, iemb, uemb, out);
}

// Round 11
// 191.524 us; speedup vs baseline: 1.0114x; 1.0114x over previous
//
#include <hip/hip_runtime.h>
#include <hip/hip_fp16.h>

// Problem constants (match reference)
#define BB      2048
#define CC      1024
#define FF      128
#define NBLK    256      // == CU count: 1 block/CU (capacity allows 2/CU)
#define RPB     8        // rows per block (NBLK*RPB == BB)
#define TPB     512      // 8 waves/block
#define NITER   10
#define SUBR    4        // colsum spread: [t][k][c], 64 adds/addr, 8 v-loads
#define SCALING_F (2048.0f / 100000.0f)

// Barrier tree geometry
#define NLEAF   8        // leaf counters per barrier slot
#define LPB     32       // blocks per leaf (NBLK/NLEAF)
#define NSLOT   (NITER + 1)   // 10 iteration barriers + 1 phase-0 barrier
#define CPAD    16       // pad counters to own 64B line

// Static device storage: no hipMalloc, graph-capture safe. All cross-block
// data moves through agent-scope atomics (serviced at the IF/LLC coherence
// point, bypassing the non-coherent per-XCD L2s) -> no cache fences needed.
// All sync counters MONOTONIC (never reset); windows from a per-launch epoch.
__device__ unsigned g_epoch;                    // launches so far * NBLK
__device__ unsigned g_leaf[NSLOT * NLEAF * CPAD];
__device__ unsigned g_root[NSLOT * CPAD];
__device__ unsigned g_rel [NSLOT * CPAD];       // release flag, own line
__device__ float g_meanPart[NBLK];              // per-block D partial sums
__device__ float g_colsum[NITER * SUBR * CC];   // [t][k][c] — c contiguous!

__device__ __forceinline__ float atomLoadF(const float* p) {
    return __hip_atomic_load(p, __ATOMIC_RELAXED, __HIP_MEMORY_SCOPE_AGENT);
}
__device__ __forceinline__ void atomStoreF(float* p, float v) {
    __hip_atomic_store(p, v, __ATOMIC_RELAXED, __HIP_MEMORY_SCOPE_AGENT);
}
__device__ __forceinline__ unsigned atomAddU(unsigned* p) {
    return __hip_atomic_fetch_add(p, 1u, __ATOMIC_RELAXED,
                                  __HIP_MEMORY_SCOPE_AGENT);
}
__device__ __forceinline__ unsigned loadU(const unsigned* p) {
    return __hip_atomic_load(p, __ATOMIC_RELAXED, __HIP_MEMORY_SCOPE_AGENT);
}
__device__ __forceinline__ void storeU(unsigned* p, unsigned v) {
    __hip_atomic_store(p, v, __ATOMIC_RELAXED, __HIP_MEMORY_SCOPE_AGENT);
}

// Tree grid barrier (proven round-6). Arrival RMWs spread over 8 leaf lines
// + 1 root line; release is a plain store to a DEDICATED line that pollers
// read -> poll traffic never interferes with arrival RMWs.
__device__ __forceinline__ void tree_barrier(int slot, unsigned e,
                                             int bid, int tid) {
    __syncthreads();
    if (tid == 0) {
        const int leaf = bid >> 5;     // 32 consecutive bids per leaf
        unsigned rl = atomAddU(&g_leaf[(slot * NLEAF + leaf) * CPAD]);
        if (rl == e * LPB + (LPB - 1)) {           // last of this leaf
            unsigned rr = atomAddU(&g_root[slot * CPAD]);
            if (rr == e * NLEAF + (NLEAF - 1))     // last leaf overall
                storeU(&g_rel[slot * CPAD], e + 1u);
        }
        while ((int)(loadU(&g_rel[slot * CPAD]) - (e + 1u)) < 0)
            ;
    }
    __syncthreads();
}

__global__ void __launch_bounds__(TPB)
fused_sinkhorn(const int* __restrict__ users, const int* __restrict__ items,
               const float* __restrict__ D, const float* __restrict__ caps,
               const float* __restrict__ iemb, const float* __restrict__ uemb,
               float* __restrict__ out) {
    const int bid = blockIdx.x, tid = threadIdx.x;
    const int r0 = bid * RPB;

    // LDS: 4 + 16 + 32 KB = ~52.5 KB/block -> 1 block/CU
    __shared__ union { float ue[RPB][FF]; float v[CC]; } uv;  // GEMM then v
    __shared__ __half dott[RPB][CC];   // 16 KB (phase0 -> phase1 only)
    __shared__ float  Kt[RPB][CC];     // 32 KB: K, phase1 to the end
    __shared__ float  ush[RPB];
    __shared__ float  red[TPB / 64];
    __shared__ float  s2sh;
    __shared__ unsigned s_epoch;

    // ---------------- phase 0 (everything independent of grid) --------------
    // launch epoch: one RMW per block; all blocks of a launch see the same
    // e = ret/NBLK because launches are stream-serialized.
    if (tid == 0) s_epoch = atomAddU(&g_epoch) >> 8;   // /NBLK

    // Register prefetches: D rows + items rows for THIS block so phase 1
    // never waits on HBM after the barrier.
    const float4* Dg  = (const float4*)(D + ((size_t)r0 << 10));
    const int4*   it4 = (const int4*)(items + ((size_t)r0 << 10));
    float4 d_reg[4];
    int4   it_reg[4];
    #pragma unroll
    for (int k = 0; k < 4; ++k) d_reg[k]  = Dg[tid + k * TPB];
    #pragma unroll
    for (int k = 0; k < 4; ++k) it_reg[k] = it4[tid + k * TPB];

    // caps for this thread's two owned columns (used every iteration + final)
    const float cap0 = caps[tid]       * SCALING_F;
    const float cap1 = caps[tid + 512] * SCALING_F;

    // zero colsum accumulators (atomic stores -> visible at IF)
    for (int i = bid * TPB + tid; i < NITER * SUBR * CC; i += NBLK * TPB)
        atomStoreF(&g_colsum[i], 0.0f);

    // stage 8 user embeddings (8 rows x 32 float4)
    if (tid < 256) {
        int r = tid >> 5, f4 = tid & 31;
        int u = users[r0 + r];
        ((float4*)uv.ue[r])[f4] = ((const float4*)(uemb + (size_t)u * FF))[f4];
    }

    // block partial sum of D (from the register prefetch)
    float p = 0.0f;
    #pragma unroll
    for (int k = 0; k < 4; ++k) {
        float4 d = d_reg[k];
        p += d.x + d.y + d.z + d.w;
    }
    #pragma unroll
    for (int off = 32; off > 0; off >>= 1) p += __shfl_down(p, off, 64);
    if ((tid & 63) == 0) red[tid >> 6] = p;
    __syncthreads();             // publishes uv.ue, red, s_epoch
    const unsigned e = s_epoch;
    if (tid == 0) {
        float s = 0.0f;
        #pragma unroll
        for (int k = 0; k < TPB / 64; ++k) s += red[k];
        atomStoreF(&g_meanPart[bid], s);
    }

    // dot GEMM: dott[r][j] = ue[r] . iemb[j].
    // 4 waves x 4 cols/lane x full K: the binding resource is the per-CU LDS
    // issue pipe; each broadcast b-read now feeds 4 output columns -> 1024
    // total ds_read_b128 (vs 2048 in the 8-wave/2-col form). Waves 4-7 idle
    // here (VALU wall is unchanged: 4 SIMDs, same total FMA count).
    if (tid < 256) {
        const float4* us  = (const float4*)uv.ue;
        const float4* ip0 = (const float4*)(iemb + (size_t)tid * FF);
        const float4* ip1 = (const float4*)(iemb + (size_t)(tid + 256) * FF);
        const float4* ip2 = (const float4*)(iemb + (size_t)(tid + 512) * FF);
        const float4* ip3 = (const float4*)(iemb + (size_t)(tid + 768) * FF);
        float acc0[RPB] = {}, acc1[RPB] = {}, acc2[RPB] = {}, acc3[RPB] = {};
        for (int f4 = 0; f4 < FF / 4; ++f4) {
            float4 a0 = ip0[f4], a1 = ip1[f4], a2 = ip2[f4], a3 = ip3[f4];
            #pragma unroll
            for (int r = 0; r < RPB; ++r) {
                float4 b = us[r * (FF / 4) + f4];   // broadcast LDS read
                acc0[r] += a0.x * b.x + a0.y * b.y + a0.z * b.z + a0.w * b.w;
                acc1[r] += a1.x * b.x + a1.y * b.y + a1.z * b.z + a1.w * b.w;
                acc2[r] += a2.x * b.x + a2.y * b.y + a2.z * b.z + a2.w * b.w;
                acc3[r] += a3.x * b.x + a3.y * b.y + a3.z * b.z + a3.w * b.w;
            }
        }
        #pragma unroll
        for (int r = 0; r < RPB; ++r) {
            dott[r][tid]       = __float2half(acc0[r]);
            dott[r][tid + 256] = __float2half(acc1[r]);
            dott[r][tid + 512] = __float2half(acc2[r]);
            dott[r][tid + 768] = __float2half(acc3[r]);
        }
    }

    tree_barrier(NITER, e, bid, tid);  // colsum zeros + meanPart complete

    // ---------------- phase 1: s2, K built in LDS (regs -> no HBM wait) -----
    if (tid < 64) {
        float s = 0.0f;
        #pragma unroll
        for (int k = 0; k < NBLK / 64; ++k)
            s += atomLoadF(&g_meanPart[tid + 64 * k]);
        #pragma unroll
        for (int off = 32; off > 0; off >>= 1) s += __shfl_down(s, off, 64);
        if (tid == 0) s2sh = 5.0f * (float)(BB * CC) / s;
    }
    __syncthreads();
    const float s2 = s2sh;
    float4* KtL = (float4*)Kt;
    #pragma unroll
    for (int k = 0; k < 4; ++k) {
        int    i  = tid + k * TPB;
        int4   iv = it_reg[k];
        float4 d  = d_reg[k];
        int    r  = i >> 8;                 // (i*4)>>10
        float4 kv;
        kv.x = __expf(5.0f * __half2float(dott[r][iv.x]) - s2 * d.x);
        kv.y = __expf(5.0f * __half2float(dott[r][iv.y]) - s2 * d.y);
        kv.z = __expf(5.0f * __half2float(dott[r][iv.z]) - s2 * d.z);
        kv.w = __expf(5.0f * __half2float(dott[r][iv.w]) - s2 * d.w);
        KtL[i] = kv;                        // K lives in LDS until the end
    }

    // ---------------- Sinkhorn iterations -----------------------------------
    for (int t = 0; t < NITER; ++t) {
        // vsh fill: v_0 = 1; else v[c] = b_c / colsum[t-1][c].
        // Explicit temps -> compiler issues the 8 relaxed atomic loads
        // back-to-back (pipelined), then sums.
        if (t == 0) {
            uv.v[tid]       = 1.0f;
            uv.v[tid + 512] = 1.0f;
        } else {
            const float* base = g_colsum + (size_t)(t - 1) * SUBR * CC;
            float t0[SUBR], t1[SUBR];
            #pragma unroll
            for (int k = 0; k < SUBR; ++k) t0[k] = atomLoadF(&base[k * CC + tid]);
            #pragma unroll
            for (int k = 0; k < SUBR; ++k) t1[k] = atomLoadF(&base[k * CC + tid + 512]);
            float s0 = 0.0f, s1 = 0.0f;
            #pragma unroll
            for (int k = 0; k < SUBR; ++k) { s0 += t0[k]; s1 += t1[k]; }
            uv.v[tid]       = cap0 / s0;
            uv.v[tid + 512] = cap1 / s1;
        }
        __syncthreads();

        // u_r = 1/(K v)_r : one wave per row
        {
            int r = tid >> 6, l = tid & 63;
            const float4* kr = (const float4*)Kt[r];
            const float4* v4 = (const float4*)uv.v;
            float pp = 0.0f;
            #pragma unroll
            for (int i2 = 0; i2 < 4; ++i2) {
                float4 k = kr[l + i2 * 64], v = v4[l + i2 * 64];
                pp += k.x * v.x + k.y * v.y + k.z * v.z + k.w * v.w;
            }
            #pragma unroll
            for (int off = 32; off > 0; off >>= 1) pp += __shfl_down(pp, off, 64);
            if (l == 0) ush[r] = 1.0f / pp;
        }
        __syncthreads();

        // colsum[t] += K^T u : 2 wave-coalesced atomicAdds per thread
        {
            float* cb = g_colsum + ((size_t)t * SUBR + (bid & (SUBR - 1))) * CC;
            float sA = 0.0f, sB = 0.0f;
            #pragma unroll
            for (int r = 0; r < RPB; ++r) {
                sA += Kt[r][tid]       * ush[r];
                sB += Kt[r][tid + 512] * ush[r];
            }
            atomicAdd(&cb[tid],       sA);
            atomicAdd(&cb[tid + 512], sB);
        }

        tree_barrier(t, e, bid, tid);  // all colsum[t] adds performed at LLC
    }

    // ---------------- final: v10 from colsum[9], P = K * u10 (x) v10 --------
    // ush still holds u10 from iteration t=9
    {
        const float* base = g_colsum + (size_t)(NITER - 1) * SUBR * CC;
        float t0[SUBR], t1[SUBR];
        #pragma unroll
        for (int k = 0; k < SUBR; ++k) t0[k] = atomLoadF(&base[k * CC + tid]);
        #pragma unroll
        for (int k = 0; k < SUBR; ++k) t1[k] = atomLoadF(&base[k * CC + tid + 512]);
        float s0 = 0.0f, s1 = 0.0f;
        #pragma unroll
        for (int k = 0; k < SUBR; ++k) { s0 += t0[k]; s1 += t1[k]; }
        uv.v[tid]       = cap0 / s0;
        uv.v[tid + 512] = cap1 / s1;
    }
    __syncthreads();

    float4* o4 = (float4*)(out + ((size_t)r0 << 10));
    #pragma unroll
    for (int k = 0; k < 4; ++k) {
        int    i  = tid + k * TPB;
        int    r  = i >> 8;
        float4 kk = KtL[i];
        float  ur = ush[r];
        float4 v  = *(const float4*)&uv.v[(i * 4) & (CC - 1)];
        float4 pv;
        pv.x = kk.x * ur * v.x;  pv.y = kk.y * ur * v.y;
        pv.z = kk.z * ur * v.z;  pv.w = kk.w * ur * v.w;
        o4[i] = pv;
    }
}

extern "C" void kernel_launch(void* const* d_in, const int* in_sizes, int n_in,
                              void* d_out, int out_size, void* d_ws, size_t ws_size,
                              hipStream_t stream) {
    const int*   users = (const int*)d_in[0];
    const int*   items = (const int*)d_in[1];
    const float* D     = (const float*)d_in[2];
    const float* caps  = (const float*)d_in[3];
    const float* iemb  = (const float*)d_in[4];
    const float* uemb  = (const float*)d_in[5];
    float* out = (float*)d_out;

    // Plain launch (graph-capture friendly). Co-residency of all 256 blocks
    // is guaranteed by capacity arithmetic (52.5 KB LDS, 8 waves -> 2
    // blocks/CU possible), which the monotonic tree barrier requires.
    hipLaunchKernelGGL(fused_sinkhorn, dim3(NBLK), dim3(TPB), 0, stream,
                       users, items, D, caps, iemb, uemb, out);
}

// Round 12
// 163.035 us; speedup vs baseline: 1.1881x; 1.1747x over previous
//
#include <hip/hip_runtime.h>
#include <hip/hip_fp16.h>

// Problem constants (match reference)
#define BB      2048
#define CC      1024
#define FF      128
#define NBLK    256      // == CU count: 1 block/CU (capacity allows 2/CU)
#define RPB     8        // rows per block (NBLK*RPB == BB)
#define TPB     512      // 8 waves/block
#define NITER   10
#define SUBR    8        // colsum spread: [t][k][c] layout, wave-coalesced
#define SCALING_F (2048.0f / 100000.0f)

// Barrier tree geometry
#define NLEAF   8        // leaf counters per barrier slot
#define LPB     32       // blocks per leaf (NBLK/NLEAF)
#define NSLOT   (NITER + 1)   // 10 iteration barriers + 1 phase-0 barrier
#define CPAD    16       // pad counters to own 64B line

// MFMA fragment types (gfx950 v_mfma_f32_16x16x32_f16: A/B = 8 x f16, C/D = 4 x f32)
typedef _Float16 v8h  __attribute__((ext_vector_type(8)));
typedef float    v4f  __attribute__((ext_vector_type(4)));

// Static device storage: no hipMalloc, graph-capture safe. All cross-block
// data moves through agent-scope atomics (serviced at the IF/LLC coherence
// point, bypassing the non-coherent per-XCD L2s) -> no cache fences needed.
// All sync counters MONOTONIC (never reset); windows from a per-launch epoch.
__device__ unsigned g_epoch;                    // launches so far * NBLK
__device__ unsigned g_leaf[NSLOT * NLEAF * CPAD];
__device__ unsigned g_root[NSLOT * CPAD];
__device__ unsigned g_rel [NSLOT * CPAD];       // release flag, own line
__device__ float g_meanPart[NBLK];              // per-block D partial sums
__device__ float g_colsum[NITER * SUBR * CC];   // [t][k][c] — c contiguous!

__device__ __forceinline__ float atomLoadF(const float* p) {
    return __hip_atomic_load(p, __ATOMIC_RELAXED, __HIP_MEMORY_SCOPE_AGENT);
}
__device__ __forceinline__ void atomStoreF(float* p, float v) {
    __hip_atomic_store(p, v, __ATOMIC_RELAXED, __HIP_MEMORY_SCOPE_AGENT);
}
__device__ __forceinline__ unsigned atomAddU(unsigned* p) {
    return __hip_atomic_fetch_add(p, 1u, __ATOMIC_RELAXED,
                                  __HIP_MEMORY_SCOPE_AGENT);
}
__device__ __forceinline__ unsigned loadU(const unsigned* p) {
    return __hip_atomic_load(p, __ATOMIC_RELAXED, __HIP_MEMORY_SCOPE_AGENT);
}
__device__ __forceinline__ void storeU(unsigned* p, unsigned v) {
    __hip_atomic_store(p, v, __ATOMIC_RELAXED, __HIP_MEMORY_SCOPE_AGENT);
}

// Tree grid barrier (proven round-6). Arrival RMWs spread over 8 leaf lines
// + 1 root line; release is a plain store to a DEDICATED line that pollers
// read -> poll traffic never interferes with arrival RMWs.
__device__ __forceinline__ void tree_barrier(int slot, unsigned e,
                                             int bid, int tid) {
    __syncthreads();
    if (tid == 0) {
        const int leaf = bid >> 5;     // 32 consecutive bids per leaf
        unsigned rl = atomAddU(&g_leaf[(slot * NLEAF + leaf) * CPAD]);
        if (rl == e * LPB + (LPB - 1)) {           // last of this leaf
            unsigned rr = atomAddU(&g_root[slot * CPAD]);
            if (rr == e * NLEAF + (NLEAF - 1))     // last leaf overall
                storeU(&g_rel[slot * CPAD], e + 1u);
        }
        while ((int)(loadU(&g_rel[slot * CPAD]) - (e + 1u)) < 0)
            ;
    }
    __syncthreads();
}

__global__ void __launch_bounds__(TPB)
fused_sinkhorn(const int* __restrict__ users, const int* __restrict__ items,
               const float* __restrict__ D, const float* __restrict__ caps,
               const float* __restrict__ iemb, const float* __restrict__ uemb,
               float* __restrict__ out) {
    const int bid = blockIdx.x, tid = threadIdx.x;
    const int r0 = bid * RPB;
    const int lane = tid & 63, wid = tid >> 6;

    // LDS: 4 + 16 + 32 KB = ~52.5 KB/block -> 1 block/CU
    __shared__ float  vsh[CC];         // 4 KB (iteration v)
    __shared__ __half dott[RPB][CC];   // 16 KB (phase0 -> phase1 only)
    __shared__ float  Kt[RPB][CC];     // 32 KB: K, phase1 to the end
    __shared__ float  ush[RPB];
    __shared__ float  red[TPB / 64];
    __shared__ float  s2sh;
    __shared__ unsigned s_epoch;

    // ---------------- phase 0 (everything independent of grid) --------------
    // launch epoch: one RMW per block; all blocks of a launch see the same
    // e = ret/NBLK because launches are stream-serialized.
    if (tid == 0) s_epoch = atomAddU(&g_epoch) >> 8;   // /NBLK

    // Register prefetches: D rows + items rows for THIS block so phase 1
    // never waits on HBM after the barrier.
    const float4* Dg  = (const float4*)(D + ((size_t)r0 << 10));
    const int4*   it4 = (const int4*)(items + ((size_t)r0 << 10));
    float4 d_reg[4];
    int4   it_reg[4];
    #pragma unroll
    for (int k = 0; k < 4; ++k) d_reg[k]  = Dg[tid + k * TPB];
    #pragma unroll
    for (int k = 0; k < 4; ++k) it_reg[k] = it4[tid + k * TPB];

    // caps for this thread's two owned columns (used every iteration + final)
    const float cap0 = caps[tid]       * SCALING_F;
    const float cap1 = caps[tid + 512] * SCALING_F;

    // zero colsum accumulators (atomic stores -> visible at IF)
    for (int i = bid * TPB + tid; i < NITER * SUBR * CC; i += NBLK * TPB)
        atomStoreF(&g_colsum[i], 0.0f);

    // block partial sum of D (from the register prefetch)
    float p = 0.0f;
    #pragma unroll
    for (int k = 0; k < 4; ++k) {
        float4 d = d_reg[k];
        p += d.x + d.y + d.z + d.w;
    }
    #pragma unroll
    for (int off = 32; off > 0; off >>= 1) p += __shfl_down(p, off, 64);
    if ((tid & 63) == 0) red[tid >> 6] = p;
    __syncthreads();             // publishes red, s_epoch
    const unsigned e = s_epoch;
    if (tid == 0) {
        float s = 0.0f;
        #pragma unroll
        for (int k = 0; k < TPB / 64; ++k) s += red[k];
        atomStoreF(&g_meanPart[bid], s);
    }

    // ---- dot GEMM via MFMA f16: dott[r][j] = ue[r].iemb[j] ------------------
    // M=8 user rows (padded to 16 with zero A rows), N=1024 item cols, K=128.
    // mfma_f32_16x16x32_f16, 4 K-steps, 8 column-tiles of 16 per wave.
    // k-mapping assumed k = ks*32 + (lane>>4)*8 + i for BOTH A and B frags:
    // any error in this mapping cancels (dot is symmetric in k) as long as
    // A and B use the same mapping. C/D layout (HW-verified, m89/m91):
    // reg i -> row=(lane>>4)*4+i, col=lane&15.
    {
        const int arow = lane & 15, kq = lane >> 4;
        v8h afrag[4];
        if (arow < RPB) {
            int u = users[r0 + arow];
            const float4* up = (const float4*)(uemb + (size_t)u * FF);
            #pragma unroll
            for (int ks = 0; ks < 4; ++ks) {
                float4 a0 = up[ks * 8 + kq * 2];
                float4 a1 = up[ks * 8 + kq * 2 + 1];
                v8h a;
                a[0] = (_Float16)a0.x; a[1] = (_Float16)a0.y;
                a[2] = (_Float16)a0.z; a[3] = (_Float16)a0.w;
                a[4] = (_Float16)a1.x; a[5] = (_Float16)a1.y;
                a[6] = (_Float16)a1.z; a[7] = (_Float16)a1.w;
                afrag[ks] = a;
            }
        } else {
            #pragma unroll
            for (int ks = 0; ks < 4; ++ks) afrag[ks] = (v8h)0;
        }
        #pragma unroll
        for (int cti = 0; cti < 8; ++cti) {
            const int ct = wid * 8 + cti;
            const int j  = ct * 16 + arow;        // B col = lane&15
            const float4* jp = (const float4*)(iemb + (size_t)j * FF);
            v4f acc = {0.f, 0.f, 0.f, 0.f};
            #pragma unroll
            for (int ks = 0; ks < 4; ++ks) {
                float4 b0 = jp[ks * 8 + kq * 2];
                float4 b1 = jp[ks * 8 + kq * 2 + 1];
                v8h b;
                b[0] = (_Float16)b0.x; b[1] = (_Float16)b0.y;
                b[2] = (_Float16)b0.z; b[3] = (_Float16)b0.w;
                b[4] = (_Float16)b1.x; b[5] = (_Float16)b1.y;
                b[6] = (_Float16)b1.z; b[7] = (_Float16)b1.w;
                acc = __builtin_amdgcn_mfma_f32_16x16x32_f16(afrag[ks], b, acc,
                                                             0, 0, 0);
            }
            if (kq < 2) {                         // rows 0-7 only
                #pragma unroll
                for (int i = 0; i < 4; ++i)
                    dott[kq * 4 + i][ct * 16 + arow] = __float2half(acc[i]);
            }
        }
    }

    tree_barrier(NITER, e, bid, tid);  // colsum zeros + meanPart complete

    // ---------------- phase 1: s2, K built in LDS (regs -> no HBM wait) -----
    if (tid < 64) {
        float s = 0.0f;
        #pragma unroll
        for (int k = 0; k < NBLK / 64; ++k)
            s += atomLoadF(&g_meanPart[tid + 64 * k]);
        #pragma unroll
        for (int off = 32; off > 0; off >>= 1) s += __shfl_down(s, off, 64);
        if (tid == 0) s2sh = 5.0f * (float)(BB * CC) / s;
    }
    __syncthreads();
    const float s2 = s2sh;
    float4* KtL = (float4*)Kt;
    #pragma unroll
    for (int k = 0; k < 4; ++k) {
        int    i  = tid + k * TPB;
        int4   iv = it_reg[k];
        float4 d  = d_reg[k];
        int    r  = i >> 8;                 // (i*4)>>10
        float4 kv;
        kv.x = __expf(5.0f * __half2float(dott[r][iv.x]) - s2 * d.x);
        kv.y = __expf(5.0f * __half2float(dott[r][iv.y]) - s2 * d.y);
        kv.z = __expf(5.0f * __half2float(dott[r][iv.z]) - s2 * d.z);
        kv.w = __expf(5.0f * __half2float(dott[r][iv.w]) - s2 * d.w);
        KtL[i] = kv;                        // K lives in LDS until the end
    }

    // ---------------- Sinkhorn iterations -----------------------------------
    for (int t = 0; t < NITER; ++t) {
        // vsh fill: v_0 = 1; else v[c] = b_c / colsum[t-1][c].
        // Explicit temps -> compiler issues the 16 relaxed atomic loads
        // back-to-back (pipelined), then sums.
        if (t == 0) {
            vsh[tid]       = 1.0f;
            vsh[tid + 512] = 1.0f;
        } else {
            const float* base = g_colsum + (size_t)(t - 1) * SUBR * CC;
            float t0[SUBR], t1[SUBR];
            #pragma unroll
            for (int k = 0; k < SUBR; ++k) t0[k] = atomLoadF(&base[k * CC + tid]);
            #pragma unroll
            for (int k = 0; k < SUBR; ++k) t1[k] = atomLoadF(&base[k * CC + tid + 512]);
            float s0 = 0.0f, s1 = 0.0f;
            #pragma unroll
            for (int k = 0; k < SUBR; ++k) { s0 += t0[k]; s1 += t1[k]; }
            vsh[tid]       = cap0 / s0;
            vsh[tid + 512] = cap1 / s1;
        }
        __syncthreads();

        // u_r = 1/(K v)_r : one wave per row
        {
            int r = tid >> 6, l = tid & 63;
            const float4* kr = (const float4*)Kt[r];
            const float4* v4 = (const float4*)vsh;
            float pp = 0.0f;
            #pragma unroll
            for (int i2 = 0; i2 < 4; ++i2) {
                float4 k = kr[l + i2 * 64], v = v4[l + i2 * 64];
                pp += k.x * v.x + k.y * v.y + k.z * v.z + k.w * v.w;
            }
            #pragma unroll
            for (int off = 32; off > 0; off >>= 1) pp += __shfl_down(pp, off, 64);
            if (l == 0) ush[r] = 1.0f / pp;
        }
        __syncthreads();

        // colsum[t] += K^T u : 2 wave-coalesced atomicAdds per thread
        {
            float* cb = g_colsum + ((size_t)t * SUBR + (bid & (SUBR - 1))) * CC;
            float sA = 0.0f, sB = 0.0f;
            #pragma unroll
            for (int r = 0; r < RPB; ++r) {
                sA += Kt[r][tid]       * ush[r];
                sB += Kt[r][tid + 512] * ush[r];
            }
            atomicAdd(&cb[tid],       sA);
            atomicAdd(&cb[tid + 512], sB);
        }

        tree_barrier(t, e, bid, tid);  // all colsum[t] adds performed at LLC
    }

    // ---------------- final: v10 from colsum[9], P = K * u10 (x) v10 --------
    // ush still holds u10 from iteration t=9
    {
        const float* base = g_colsum + (size_t)(NITER - 1) * SUBR * CC;
        float t0[SUBR], t1[SUBR];
        #pragma unroll
        for (int k = 0; k < SUBR; ++k) t0[k] = atomLoadF(&base[k * CC + tid]);
        #pragma unroll
        for (int k = 0; k < SUBR; ++k) t1[k] = atomLoadF(&base[k * CC + tid + 512]);
        float s0 = 0.0f, s1 = 0.0f;
        #pragma unroll
        for (int k = 0; k < SUBR; ++k) { s0 += t0[k]; s1 += t1[k]; }
        vsh[tid]       = cap0 / s0;
        vsh[tid + 512] = cap1 / s1;
    }
    __syncthreads();

    float4* o4 = (float4*)(out + ((size_t)r0 << 10));
    #pragma unroll
    for (int k = 0; k < 4; ++k) {
        int    i  = tid + k * TPB;
        int    r  = i >> 8;
        float4 kk = KtL[i];
        float  ur = ush[r];
        float4 v  = *(const float4*)&vsh[(i * 4) & (CC - 1)];
        float4 pv;
        pv.x = kk.x * ur * v.x;  pv.y = kk.y * ur * v.y;
        pv.z = kk.z * ur * v.z;  pv.w = kk.w * ur * v.w;
        o4[i] = pv;
    }
}

extern "C" void kernel_launch(void* const* d_in, const int* in_sizes, int n_in,
                              void* d_out, int out_size, void* d_ws, size_t ws_size,
                              hipStream_t stream) {
    const int*   users = (const int*)d_in[0];
    const int*   items = (const int*)d_in[1];
    const float* D     = (const float*)d_in[2];
    const float* caps  = (const float*)d_in[3];
    const float* iemb  = (const float*)d_in[4];
    const float* uemb  = (const float*)d_in[5];
    float* out = (float*)d_out;

    // Plain launch (graph-capture friendly). Co-residency of all 256 blocks
    // is guaranteed by capacity arithmetic (52.5 KB LDS, 8 waves -> 2
    // blocks/CU possible), which the monotonic tree barrier requires.
    hipLaunchKernelGGL(fused_sinkhorn, dim3(NBLK), dim3(TPB), 0, stream,
                       users, items, D, caps, iemb, uemb, out);
}